// Round 6
// baseline (1067.431 us; speedup 1.0000x reference)
//
#include <hip/hip_runtime.h>
#include <hip/hip_bf16.h>

typedef _Float16 f16;
typedef _Float16 half8 __attribute__((ext_vector_type(8)));
typedef _Float16 half4v __attribute__((ext_vector_type(4)));
typedef float f32x4 __attribute__((ext_vector_type(4)));

#define B_ 4
#define S_ 3072
#define D_ 768
#define E_ 2000
#define NEG_INF -1.0e6f

// async global->LDS, 16B per lane; per-lane global src, linear LDS dest
#define GLD16(gsrc, ldst)                                                     \
  __builtin_amdgcn_global_load_lds(                                           \
      (const __attribute__((address_space(1))) void*)(gsrc),                  \
      (__attribute__((address_space(3))) void*)(ldst), 16, 0, 0)

// ---------------------------------------------------------------------------
// h [B,S,D] f32  ->  ht [B,D,S] f16   (LDS-tiled transpose, 64x64)
// ---------------------------------------------------------------------------
__global__ __launch_bounds__(256) void k_transpose(const float* __restrict__ h,
                                                   f16* __restrict__ ht) {
  __shared__ f16 tile[64][65];
  int b = blockIdx.z, s0 = blockIdx.x * 64, d0 = blockIdx.y * 64;
  int t = threadIdx.x, tx = t & 63, ty = t >> 6;
  const float* src = h + ((size_t)b * S_ + s0) * D_ + d0;
#pragma unroll
  for (int i = 0; i < 16; ++i) {
    int sl = i * 4 + ty;
    tile[sl][tx] = (f16)src[(size_t)sl * D_ + tx];
  }
  __syncthreads();
  f16* dst = ht + ((size_t)b * D_ + d0) * S_ + s0;
#pragma unroll
  for (int i = 0; i < 16; ++i) {
    int dl = i * 4 + ty;
    dst[(size_t)dl * S_ + tx] = tile[tx][dl];
  }
}

// ---------------------------------------------------------------------------
// z = tanh(h @ W^T + bias) -> zb f16 [B*S, D]
// ---------------------------------------------------------------------------
__global__ __launch_bounds__(256) void k_zgemm(const float* __restrict__ h,
                                               const float* __restrict__ W,
                                               const float* __restrict__ bias,
                                               f16* __restrict__ zb) {
  __shared__ f16 As[64][40];
  __shared__ f16 Bs[64][40];
  int i0 = blockIdx.x * 64, j0 = blockIdx.y * 64;
  int t = threadIdx.x, w = t >> 6, lane = t & 63, g = lane >> 4, li = lane & 15;
  int wi = w >> 1, wj = w & 1;

  f32x4 acc[2][2];
#pragma unroll
  for (int a = 0; a < 2; ++a)
#pragma unroll
    for (int b2 = 0; b2 < 2; ++b2) acc[a][b2] = (f32x4){0.f, 0.f, 0.f, 0.f};

  int srow = t >> 2, scol = (t & 3) * 8;
  const float* pA = h + (size_t)(i0 + srow) * D_ + scol;
  const float* pB = W + (size_t)(j0 + srow) * D_ + scol;

  for (int kc = 0; kc < D_; kc += 32) {
    float4 a0 = *(const float4*)(pA + kc);
    float4 a1 = *(const float4*)(pA + kc + 4);
    float4 b0 = *(const float4*)(pB + kc);
    float4 b1 = *(const float4*)(pB + kc + 4);
    half8 av = {(f16)a0.x, (f16)a0.y, (f16)a0.z, (f16)a0.w,
                (f16)a1.x, (f16)a1.y, (f16)a1.z, (f16)a1.w};
    half8 bv = {(f16)b0.x, (f16)b0.y, (f16)b0.z, (f16)b0.w,
                (f16)b1.x, (f16)b1.y, (f16)b1.z, (f16)b1.w};
    *(half8*)&As[srow][scol] = av;
    *(half8*)&Bs[srow][scol] = bv;
    __syncthreads();
#pragma unroll
    for (int it = 0; it < 2; ++it) {
      half8 af = *(const half8*)&As[wi * 32 + it * 16 + li][g * 8];
#pragma unroll
      for (int jt = 0; jt < 2; ++jt) {
        half8 bf = *(const half8*)&Bs[wj * 32 + jt * 16 + li][g * 8];
        acc[it][jt] =
            __builtin_amdgcn_mfma_f32_16x16x32_f16(af, bf, acc[it][jt], 0, 0, 0);
      }
    }
    __syncthreads();
  }
#pragma unroll
  for (int it = 0; it < 2; ++it) {
#pragma unroll
    for (int jt = 0; jt < 2; ++jt) {
      int jj = j0 + wj * 32 + jt * 16 + li;
      float bsv = bias[jj];
#pragma unroll
      for (int r = 0; r < 4; ++r) {
        int ii = i0 + wi * 32 + it * 16 + g * 4 + r;
        float v = acc[it][jt][r] + bsv;
        zb[(size_t)ii * D_ + jj] = (f16)tanhf(v);
      }
    }
  }
}

// ---------------------------------------------------------------------------
// Fused flash attention + head max-pool, v6.
// 8 waves, 64 q, 32-key tiles.  2 raw s_barriers per tile, counted vmcnt:
//  seg1: [K(i+1) DMA issue][V(i)->reg issue] PV(i-1) from Vreg | QK(i) | Cp
//        lgkmcnt(0); s_barrier
//  seg2: kh0 softmax -> Pt/Fac | vmcnt(6) lgkmcnt(0) (K landed, V in flight)
//        s_barrier
// V is per-wave-disjoint (d-split) -> registers, 1-iteration prefetch,
// double reg buffer via 2x-unrolled body (static indexing, no scratch).
// ---------------------------------------------------------------------------
__global__ __launch_bounds__(512, 1) void k_attn(const float* __restrict__ lf,
                                                 const f16* __restrict__ zb,
                                                 const f16* __restrict__ ht,
                                                 const int* __restrict__ amask,
                                                 float* __restrict__ out_m) {
  __shared__ f16 KsBuf[2][32 * 768];  // 98304 B, XOR-swizzled rows (1536 B)
  __shared__ f16 PtBuf[64 * 32];      // 4096 B, swizzle ((li>>1)&3)<<4
  __shared__ float Cp[32][68];        // 8704 B
  __shared__ float Fac[64];
  __shared__ float Lfin[64];
  __shared__ int Msk[2][32];

  char* KsB = (char*)&KsBuf[0][0];
  char* PtB = (char*)PtBuf;

  // ---- XCD-grouping swizzle (grid = 512 flat, 12 dead blocks)
  const int fid = blockIdx.x;
  const int x2 = fid & 7, u = fid >> 3;
  const int b = x2 >> 1;
  const int qtile = (x2 & 1) * 64 + u;
  if (qtile >= 125) return;
  const int q0 = qtile * 64;

  const int t = threadIdx.x, w = t >> 6, lane = t & 63;
  const int g = lane >> 4, li = lane & 15;
  const int qt = w & 3, kh = w >> 2;  // QK + softmax roles
  const int dh = w;                   // PV role: 96-d block

  // ---- Q fragments: 16 q x 384-k half, direct from global f32 -> f16
  half8 qf[12];
  {
    const float* qp = lf + (size_t)(q0 + qt * 16 + li) * D_ + kh * 384 + g * 8;
#pragma unroll
    for (int f = 0; f < 12; ++f) {
      float4 v0 = *(const float4*)(qp + f * 32);
      float4 v1 = *(const float4*)(qp + f * 32 + 4);
      qf[f] = (half8){(f16)v0.x, (f16)v0.y, (f16)v0.z, (f16)v0.w,
                      (f16)v1.x, (f16)v1.y, (f16)v1.z, (f16)v1.w};
    }
  }

  // ---- K staging: 6 chunks/thread; LDS linear, global pre-swizzled
  int klds[6], kgsw[6];
#pragma unroll
  for (int k = 0; k < 6; ++k) {
    int lin = (w * 6 + k) * 1024 + lane * 16;
    int row = lin / 1536;
    int xo = lin - row * 1536;
    klds[k] = lin;
    kgsw[k] = row * 1536 + (xo ^ ((row & 7) << 4));
  }

  // ---- QK A-frag bases
  const int amask7 = (li & 7) << 4;
  const int arow0 = li * 1536 + kh * 768;
  const int arow1 = (16 + li) * 1536 + kh * 768;

  // ---- Pt offsets (swizzle f(row)=((row>>1)&3)<<4, row%16==li both sides)
  const int pswz = ((li >> 1) & 3) << 4;
  int ptoff[4];
#pragma unroll
  for (int qs = 0; qs < 4; ++qs)
    ptoff[qs] = (qs * 16 + li) * 64 + ((g * 16) ^ pswz);
  const int pwoff0 = (qt * 16 + li) * 64 + ((g * 8) ^ pswz);
  const int pwoff1 = (qt * 16 + li) * 64 + ((32 + g * 8) ^ pswz);

  const char* zbB = (const char*)zb + (size_t)b * S_ * 1536;
  const f16* vbase = ht + ((size_t)b * D_ + dh * 96 + li) * S_ + g * 8;

  // ---- prologue: DMA K(0) into buf 0
#pragma unroll
  for (int k = 0; k < 6; ++k) GLD16(zbB + kgsw[k], KsB + klds[k]);
  if (t < 32) Msk[0][t] = amask[b * S_ + t];
  asm volatile("s_waitcnt vmcnt(0)" ::: "memory");
  __syncthreads();

  float mreg = -3.0e38f, lreg = 0.0f;
  f32x4 oacc[4][6];  // [q-subtile][d-subtile of my 96-d block]
#pragma unroll
  for (int a = 0; a < 4; ++a)
#pragma unroll
    for (int d = 0; d < 6; ++d) oacc[a][d] = (f32x4){0.f, 0.f, 0.f, 0.f};

  half8 Vb0[6], Vb1[6];

#define ATT_BODY(I_, VRD, VWR)                                                \
  {                                                                           \
    const int i_ = (I_);                                                      \
    const int s0_ = i_ * 32;                                                  \
    const int s0n_ = (i_ < 95) ? s0_ + 32 : 0;                                \
    const char* ksC_ = KsB + (i_ & 1) * 49152;                                \
    char* ksN_ = KsB + ((i_ & 1) ^ 1) * 49152;                                \
    int mnext_ = (t < 32) ? amask[b * S_ + s0n_ + t] : 0;                     \
    { /* K(i+1) DMA first: oldest in vmcnt queue */                           \
      const char* src_ = zbB + (size_t)s0n_ * 1536;                           \
      _Pragma("unroll") for (int k = 0; k < 6; ++k)                           \
          GLD16(src_ + kgsw[k], ksN_ + klds[k]);                              \
    }                                                                         \
    { /* V(i) -> VWR regs (consumed next iteration) */                        \
      const f16* vp_ = vbase + s0_;                                           \
      _Pragma("unroll") for (int dt = 0; dt < 6; ++dt)                        \
          VWR[dt] = *(const half8*)(vp_ + (size_t)dt * 16 * S_);              \
    }                                                                         \
    __builtin_amdgcn_sched_barrier(0);                                        \
    if (i_ > 0) { /* PV(i-1): rescale + MFMA from VRD */                      \
      float fr_[4][4];                                                        \
      _Pragma("unroll") for (int qs = 0; qs < 4; ++qs)                        \
          _Pragma("unroll") for (int r = 0; r < 4; ++r)                       \
              fr_[qs][r] = Fac[qs * 16 + g * 4 + r];                          \
      _Pragma("unroll") for (int qs = 0; qs < 4; ++qs)                        \
          _Pragma("unroll") for (int dt = 0; dt < 6; ++dt)                    \
              _Pragma("unroll") for (int r = 0; r < 4; ++r)                   \
                  oacc[qs][dt][r] *= fr_[qs][r];                              \
      half8 pa_[4];                                                           \
      _Pragma("unroll") for (int qs = 0; qs < 4; ++qs)                        \
          pa_[qs] = *(const half8*)(PtB + ptoff[qs]);                         \
      __builtin_amdgcn_s_setprio(1);                                          \
      _Pragma("unroll") for (int dt = 0; dt < 6; ++dt)                        \
          _Pragma("unroll") for (int qs = 0; qs < 4; ++qs)                    \
              oacc[qs][dt] = __builtin_amdgcn_mfma_f32_16x16x32_f16(          \
                  pa_[qs], VRD[dt], oacc[qs][dt], 0, 0, 0);                   \
      __builtin_amdgcn_s_setprio(0);                                          \
    }                                                                         \
    /* QK(i): 16q x 32s over this wave's 384-k half */                        \
    f32x4 c0_ = {0.f, 0.f, 0.f, 0.f}, c1_ = {0.f, 0.f, 0.f, 0.f};             \
    f32x4 e0_ = {0.f, 0.f, 0.f, 0.f}, e1_ = {0.f, 0.f, 0.f, 0.f};             \
    __builtin_amdgcn_s_setprio(1);                                            \
    _Pragma("unroll") for (int kf = 0; kf < 6; ++kf) {                        \
      const int col = (kf * 64 + g * 16) ^ amask7;                            \
      half8 a0 = *(const half8*)(ksC_ + arow0 + col);                         \
      half8 a1 = *(const half8*)(ksC_ + arow1 + col);                         \
      c0_ = __builtin_amdgcn_mfma_f32_16x16x32_f16(a0, qf[kf], c0_, 0, 0, 0); \
      c1_ = __builtin_amdgcn_mfma_f32_16x16x32_f16(a1, qf[kf], c1_, 0, 0, 0); \
    }                                                                         \
    _Pragma("unroll") for (int kf = 6; kf < 12; ++kf) {                       \
      const int col = (kf * 64 + g * 16) ^ amask7;                            \
      half8 a0 = *(const half8*)(ksC_ + arow0 + col);                         \
      half8 a1 = *(const half8*)(ksC_ + arow1 + col);                         \
      e0_ = __builtin_amdgcn_mfma_f32_16x16x32_f16(a0, qf[kf], e0_, 0, 0, 0); \
      e1_ = __builtin_amdgcn_mfma_f32_16x16x32_f16(a1, qf[kf], e1_, 0, 0, 0); \
    }                                                                         \
    __builtin_amdgcn_s_setprio(0);                                            \
    c0_ = c0_ + e0_;                                                          \
    c1_ = c1_ + e1_;                                                          \
    if (kh == 1) {                                                            \
      _Pragma("unroll") for (int r = 0; r < 4; ++r) {                         \
        Cp[g * 4 + r][qt * 16 + li] = c0_[r];                                 \
        Cp[16 + g * 4 + r][qt * 16 + li] = c1_[r];                            \
      }                                                                       \
    }                                                                         \
    asm volatile("s_waitcnt lgkmcnt(0)" ::: "memory");                        \
    __builtin_amdgcn_s_barrier(); /* bar B */                                 \
    if (kh == 0) {                                                            \
      const int* mk_ = Msk[i_ & 1];                                           \
      float p_[8];                                                            \
      float vmax_ = -3.0e38f;                                                 \
      _Pragma("unroll") for (int r = 0; r < 4; ++r) {                         \
        float sv0 = c0_[r] + Cp[g * 4 + r][qt * 16 + li];                     \
        float sv1 = c1_[r] + Cp[16 + g * 4 + r][qt * 16 + li];                \
        if (!mk_[g * 4 + r]) sv0 = NEG_INF;                                   \
        if (!mk_[16 + g * 4 + r]) sv1 = NEG_INF;                              \
        p_[r] = sv0;                                                          \
        p_[4 + r] = sv1;                                                      \
        vmax_ = fmaxf(vmax_, fmaxf(sv0, sv1));                                \
      }                                                                       \
      vmax_ = fmaxf(vmax_, __shfl_xor(vmax_, 16));                            \
      vmax_ = fmaxf(vmax_, __shfl_xor(vmax_, 32));                            \
      float Mn_ = fmaxf(mreg, vmax_);                                         \
      float fec_ = __expf(mreg - Mn_);                                        \
      mreg = Mn_;                                                             \
      float ts_ = 0.f;                                                        \
      _Pragma("unroll") for (int r = 0; r < 8; ++r) {                         \
        p_[r] = __expf(p_[r] - Mn_);                                          \
        ts_ += p_[r];                                                         \
      }                                                                       \
      ts_ += __shfl_xor(ts_, 16);                                             \
      ts_ += __shfl_xor(ts_, 32);                                             \
      lreg = lreg * fec_ + ts_;                                               \
      if (lane < 16) Fac[qt * 16 + li] = fec_;                                \
      *(half4v*)(PtB + pwoff0) =                                              \
          (half4v){(f16)p_[0], (f16)p_[1], (f16)p_[2], (f16)p_[3]};           \
      *(half4v*)(PtB + pwoff1) =                                              \
          (half4v){(f16)p_[4], (f16)p_[5], (f16)p_[6], (f16)p_[7]};           \
    }                                                                         \
    if (t < 32) Msk[(i_ + 1) & 1][t] = mnext_;                                \
    asm volatile("s_waitcnt vmcnt(6) lgkmcnt(0)" ::: "memory");               \
    __builtin_amdgcn_s_barrier(); /* bar C: K(i+1)/Pt/Fac ready */            \
  }

  for (int ii = 0; ii < 96; ii += 2) {
    ATT_BODY(ii, Vb1, Vb0)
    ATT_BODY(ii + 1, Vb0, Vb1)
  }
#undef ATT_BODY

  // ---- final PV (tile 95, V in Vb1) ----
  {
    float fr_[4][4];
#pragma unroll
    for (int qs = 0; qs < 4; ++qs)
#pragma unroll
      for (int r = 0; r < 4; ++r) fr_[qs][r] = Fac[qs * 16 + g * 4 + r];
#pragma unroll
    for (int qs = 0; qs < 4; ++qs)
#pragma unroll
      for (int dt = 0; dt < 6; ++dt)
#pragma unroll
        for (int r = 0; r < 4; ++r) oacc[qs][dt][r] *= fr_[qs][r];
    half8 pa_[4];
#pragma unroll
    for (int qs = 0; qs < 4; ++qs) pa_[qs] = *(const half8*)(PtB + ptoff[qs]);
#pragma unroll
    for (int dt = 0; dt < 6; ++dt)
#pragma unroll
      for (int qs = 0; qs < 4; ++qs)
        oacc[qs][dt] = __builtin_amdgcn_mfma_f32_16x16x32_f16(
            pa_[qs], Vb1[dt], oacc[qs][dt], 0, 0, 0);
  }

  if (kh == 0 && lane < 16) Lfin[qt * 16 + li] = lreg;
  __syncthreads();

  // ---- epilogue: O/l, head max-pool over r (4 heads per label), store ----
#pragma unroll
  for (int qs = 0; qs < 4; ++qs) {
    float rl[4];
#pragma unroll
    for (int r = 0; r < 4; ++r) rl[r] = 1.0f / Lfin[qs * 16 + g * 4 + r];
    int e_loc = qs * 4 + g;
    float* od = out_m + ((size_t)b * E_ + (q0 >> 2) + e_loc) * D_ + dh * 96 + li;
#pragma unroll
    for (int dt = 0; dt < 6; ++dt) {
      float mv = oacc[qs][dt][0] * rl[0];
      mv = fmaxf(mv, oacc[qs][dt][1] * rl[1]);
      mv = fmaxf(mv, oacc[qs][dt][2] * rl[2]);
      mv = fmaxf(mv, oacc[qs][dt][3] * rl[3]);
      od[dt * 16] = mv;
    }
  }
}

// ---------------------------------------------------------------------------
// logits[b,e] = sum_d cls_w[e,d]*m[b,e,d] + cls_b[e]; one wave per (b,e)
// ---------------------------------------------------------------------------
__global__ __launch_bounds__(256) void k_logits(const float* __restrict__ cw,
                                                const float* __restrict__ cb,
                                                const float* __restrict__ m,
                                                float* __restrict__ out) {
  int t = threadIdx.x, w = t >> 6, lane = t & 63;
  int rid = blockIdx.x * 4 + w;  // 0..7999
  int b = rid / E_, e = rid - b * E_;
  const float* mr = m + (size_t)rid * D_;
  const float* cr = cw + (size_t)e * D_;
  float acc = 0.f;
#pragma unroll
  for (int i = 0; i < 12; ++i) acc += cr[i * 64 + lane] * mr[i * 64 + lane];
#pragma unroll
  for (int off = 32; off >= 1; off >>= 1) acc += __shfl_xor(acc, off);
  if (lane == 0) out[rid] = acc + cb[e];
}

// ---------------------------------------------------------------------------
extern "C" void kernel_launch(void* const* d_in, const int* in_sizes, int n_in,
                              void* d_out, int out_size, void* d_ws, size_t ws_size,
                              hipStream_t stream) {
  const float* h = (const float*)d_in[0];
  const int* amask = (const int*)d_in[1];
  const float* lf = (const float*)d_in[2];
  const float* Ww = (const float*)d_in[3];
  const float* Wb = (const float*)d_in[4];
  const float* cw = (const float*)d_in[5];
  const float* cb = (const float*)d_in[6];
  float* out = (float*)d_out;

  f16* zb = (f16*)d_ws;                     // 12288*768*2 = 18874368 B
  f16* ht = (f16*)((char*)d_ws + 18874368); // 4*768*3072*2 = 18874368 B

  k_transpose<<<dim3(48, 12, 4), 256, 0, stream>>>(h, ht);
  k_zgemm<<<dim3(192, 12), 256, 0, stream>>>(h, Ww, Wb, zb);
  k_attn<<<512, 512, 0, stream>>>(lf, zb, ht, amask, out + 8000);
  k_logits<<<2000, 256, 0, stream>>>(cw, cb, out + 8000, out);
}

// Round 7
// 614.309 us; speedup vs baseline: 1.7376x; 1.7376x over previous
//
#include <hip/hip_runtime.h>
#include <hip/hip_bf16.h>

typedef _Float16 f16;
typedef _Float16 half8 __attribute__((ext_vector_type(8)));
typedef _Float16 half4v __attribute__((ext_vector_type(4)));
typedef float f32x4 __attribute__((ext_vector_type(4)));

#define B_ 4
#define S_ 3072
#define D_ 768
#define E_ 2000
#define NEG_INF -1.0e6f

// async global->LDS, 16B per lane; per-lane global src, linear LDS dest
#define GLD16(gsrc, ldst)                                                     \
  __builtin_amdgcn_global_load_lds(                                           \
      (const __attribute__((address_space(1))) void*)(gsrc),                  \
      (__attribute__((address_space(3))) void*)(ldst), 16, 0, 0)

// ---------------------------------------------------------------------------
// h [B,S,D] f32  ->  ht [B,D,S] f16   (LDS-tiled transpose, 64x64)
// ---------------------------------------------------------------------------
__global__ __launch_bounds__(256) void k_transpose(const float* __restrict__ h,
                                                   f16* __restrict__ ht) {
  __shared__ f16 tile[64][65];
  int b = blockIdx.z, s0 = blockIdx.x * 64, d0 = blockIdx.y * 64;
  int t = threadIdx.x, tx = t & 63, ty = t >> 6;
  const float* src = h + ((size_t)b * S_ + s0) * D_ + d0;
#pragma unroll
  for (int i = 0; i < 16; ++i) {
    int sl = i * 4 + ty;
    tile[sl][tx] = (f16)src[(size_t)sl * D_ + tx];
  }
  __syncthreads();
  f16* dst = ht + ((size_t)b * D_ + d0) * S_ + s0;
#pragma unroll
  for (int i = 0; i < 16; ++i) {
    int dl = i * 4 + ty;
    dst[(size_t)dl * S_ + tx] = tile[tx][dl];
  }
}

// ---------------------------------------------------------------------------
// z = tanh(h @ W^T + bias) -> zb f16 [B*S, D]
// ---------------------------------------------------------------------------
__global__ __launch_bounds__(256) void k_zgemm(const float* __restrict__ h,
                                               const float* __restrict__ W,
                                               const float* __restrict__ bias,
                                               f16* __restrict__ zb) {
  __shared__ f16 As[64][40];
  __shared__ f16 Bs[64][40];
  int i0 = blockIdx.x * 64, j0 = blockIdx.y * 64;
  int t = threadIdx.x, w = t >> 6, lane = t & 63, g = lane >> 4, li = lane & 15;
  int wi = w >> 1, wj = w & 1;

  f32x4 acc[2][2];
#pragma unroll
  for (int a = 0; a < 2; ++a)
#pragma unroll
    for (int b2 = 0; b2 < 2; ++b2) acc[a][b2] = (f32x4){0.f, 0.f, 0.f, 0.f};

  int srow = t >> 2, scol = (t & 3) * 8;
  const float* pA = h + (size_t)(i0 + srow) * D_ + scol;
  const float* pB = W + (size_t)(j0 + srow) * D_ + scol;

  for (int kc = 0; kc < D_; kc += 32) {
    float4 a0 = *(const float4*)(pA + kc);
    float4 a1 = *(const float4*)(pA + kc + 4);
    float4 b0 = *(const float4*)(pB + kc);
    float4 b1 = *(const float4*)(pB + kc + 4);
    half8 av = {(f16)a0.x, (f16)a0.y, (f16)a0.z, (f16)a0.w,
                (f16)a1.x, (f16)a1.y, (f16)a1.z, (f16)a1.w};
    half8 bv = {(f16)b0.x, (f16)b0.y, (f16)b0.z, (f16)b0.w,
                (f16)b1.x, (f16)b1.y, (f16)b1.z, (f16)b1.w};
    *(half8*)&As[srow][scol] = av;
    *(half8*)&Bs[srow][scol] = bv;
    __syncthreads();
#pragma unroll
    for (int it = 0; it < 2; ++it) {
      half8 af = *(const half8*)&As[wi * 32 + it * 16 + li][g * 8];
#pragma unroll
      for (int jt = 0; jt < 2; ++jt) {
        half8 bf = *(const half8*)&Bs[wj * 32 + jt * 16 + li][g * 8];
        acc[it][jt] =
            __builtin_amdgcn_mfma_f32_16x16x32_f16(af, bf, acc[it][jt], 0, 0, 0);
      }
    }
    __syncthreads();
  }
#pragma unroll
  for (int it = 0; it < 2; ++it) {
#pragma unroll
    for (int jt = 0; jt < 2; ++jt) {
      int jj = j0 + wj * 32 + jt * 16 + li;
      float bsv = bias[jj];
#pragma unroll
      for (int r = 0; r < 4; ++r) {
        int ii = i0 + wi * 32 + it * 16 + g * 4 + r;
        float v = acc[it][jt][r] + bsv;
        zb[(size_t)ii * D_ + jj] = (f16)tanhf(v);
      }
    }
  }
}

// ---------------------------------------------------------------------------
// Fused flash attention + head max-pool, v7 = v5 + raw barriers/counted
// vmcnt + pinned 2-waves/EU regalloc (no spill).
// Block: 512 thr (8 waves), 64 queries, S in 32-key tiles.
//  seg1: [mask ld][V(i) DMA] QK(i) from Ks[cur] | [K(i+1) DMA] | Cp
//        lgkmcnt(0); s_barrier                                        (bar B)
//  seg2: kh0 softmax (m,l regs) -> Pt/Fac | Msk store
//        vmcnt(6) lgkmcnt(0)  <- V landed, 6 K-DMAs stay in flight
//        s_barrier                                                    (bar C)
//  seg3: PV(i) from Vs LDS (d-split dh 0..7)
//        vmcnt(0)  <- K(i+1) landed (window = whole iteration)
//        s_barrier                                                    (bar D)
// ---------------------------------------------------------------------------
__global__ __launch_bounds__(512)
__attribute__((amdgpu_waves_per_eu(2, 2)))
void k_attn(const float* __restrict__ lf,
            const f16* __restrict__ zb,
            const f16* __restrict__ ht,
            const int* __restrict__ amask,
            float* __restrict__ out_m) {
  __shared__ f16 KsBuf[2][32 * 768];  // 98304 B, XOR-swizzled rows (1536 B)
  __shared__ f16 VsBuf[768 * 32];     // 49152 B, XOR-swizzled rows (64 B)
  __shared__ f16 PtBuf[64 * 32];      // 4096 B
  __shared__ float Cp[32][68];        // 8704 B
  __shared__ float Fac[64];
  __shared__ float Lfin[64];
  __shared__ int Msk[2][32];

  char* KsB = (char*)&KsBuf[0][0];
  char* VsB = (char*)VsBuf;
  char* PtB = (char*)PtBuf;

  // ---- XCD-grouping swizzle (grid = 512 flat, 12 dead blocks)
  const int fid = blockIdx.x;
  const int x2 = fid & 7, u = fid >> 3;  // u: 0..63
  const int b = x2 >> 1;
  const int qtile = (x2 & 1) * 64 + u;
  if (qtile >= 125) return;
  const int q0 = qtile * 64;

  const int t = threadIdx.x, w = t >> 6, lane = t & 63;
  const int g = lane >> 4, li = lane & 15;
  const int qt = w & 3, kh = w >> 2;  // QK + softmax roles
  const int dh = w;                   // PV role: 96-d block

  // ---- Q fragments: 16 q x 384-k half, direct from global f32 -> f16
  half8 qf[12];
  {
    const float* qp = lf + (size_t)(q0 + qt * 16 + li) * D_ + kh * 384 + g * 8;
#pragma unroll
    for (int f = 0; f < 12; ++f) {
      float4 v0 = *(const float4*)(qp + f * 32);
      float4 v1 = *(const float4*)(qp + f * 32 + 4);
      qf[f] = (half8){(f16)v0.x, (f16)v0.y, (f16)v0.z, (f16)v0.w,
                      (f16)v1.x, (f16)v1.y, (f16)v1.z, (f16)v1.w};
    }
  }

  // ---- K staging: 6 chunks/thread; LDS linear, global pre-swizzled
  int klds[6], kgsw[6];
#pragma unroll
  for (int k = 0; k < 6; ++k) {
    int lin = (w * 6 + k) * 1024 + lane * 16;
    int row = lin / 1536;
    int xo = lin - row * 1536;
    klds[k] = lin;
    kgsw[k] = row * 1536 + (xo ^ ((row & 7) << 4));
  }
  // ---- V staging: tile ht[b][d][s0..s0+32] -> Vs[d][32s] rows of 64 B
  int vlds[6], vgsw[6];
#pragma unroll
  for (int k = 0; k < 6; ++k) {
    int j = w * 6 + k;
    int vd = j * 16 + (lane >> 2);
    vlds[k] = j * 1024 + lane * 16;
    vgsw[k] = vd * (S_ * 2) + (((lane & 3) * 16) ^ ((vd & 3) << 4));
  }

  // ---- QK A-frag bases
  const int amask7 = (li & 7) << 4;
  const int arow0 = li * 1536 + kh * 768;
  const int arow1 = (16 + li) * 1536 + kh * 768;

  // ---- PV read offsets: V rows d = dh*96 + dt*16 + li
  const int vroff = (dh * 96 + li) * 64 + ((g * 16) ^ ((li & 3) << 4));
  int ptoff[4];
#pragma unroll
  for (int qs = 0; qs < 4; ++qs)
    ptoff[qs] = (qs * 16 + li) * 64 + ((g * 16) ^ ((li & 3) << 4));

  // ---- P write offsets (kh0 softmax): row = qt*16+li
  const int pwoff0 = (qt * 16 + li) * 64 + ((g * 8) ^ ((li & 3) << 4));
  const int pwoff1 = (qt * 16 + li) * 64 + ((32 + g * 8) ^ ((li & 3) << 4));

  const char* zbB = (const char*)zb + (size_t)b * S_ * 1536;
  const char* htB = (const char*)ht + (size_t)b * D_ * S_ * 2;

  // ---- prologue: DMA K(0) into buf 0
#pragma unroll
  for (int k = 0; k < 6; ++k) GLD16(zbB + kgsw[k], KsB + klds[k]);
  if (t < 32) Msk[0][t] = amask[b * S_ + t];
  asm volatile("s_waitcnt vmcnt(0)" ::: "memory");
  __syncthreads();

  float mreg = -3.0e38f, lreg = 0.0f;
  f32x4 oacc[4][6];  // [q-subtile][d-subtile of my 96-d block]
#pragma unroll
  for (int a = 0; a < 4; ++a)
#pragma unroll
    for (int d = 0; d < 6; ++d) oacc[a][d] = (f32x4){0.f, 0.f, 0.f, 0.f};

  for (int i = 0; i < 96; ++i) {
    const int s0 = i * 32;
    const int s0n = (i < 95) ? s0 + 32 : 0;
    const int cur = i & 1, nxt = cur ^ 1;
    const char* ksC = KsB + cur * 49152;

    // ================= seg1 =================
    // mask load first (oldest in vmcnt queue for wave 0)
    int mnext = (t < 32) ? amask[b * S_ + s0n + t] : 0;
    // issue V(i) DMA (VsBuf reads finished at barrier D of i-1)
    {
      const char* src = htB + (size_t)s0 * 2;
#pragma unroll
      for (int k = 0; k < 6; ++k) GLD16(src + vgsw[k], VsB + vlds[k]);
    }

    // QK(i): 16q x 32s over this wave's 384-k half; 4 independent chains
    f32x4 c0 = {0.f, 0.f, 0.f, 0.f}, c1 = {0.f, 0.f, 0.f, 0.f};
    f32x4 e0 = {0.f, 0.f, 0.f, 0.f}, e1 = {0.f, 0.f, 0.f, 0.f};
    __builtin_amdgcn_s_setprio(1);
#pragma unroll
    for (int kf = 0; kf < 6; ++kf) {
      const int col = (kf * 64 + g * 16) ^ amask7;
      half8 a0 = *(const half8*)(ksC + arow0 + col);
      half8 a1 = *(const half8*)(ksC + arow1 + col);
      c0 = __builtin_amdgcn_mfma_f32_16x16x32_f16(a0, qf[kf], c0, 0, 0, 0);
      c1 = __builtin_amdgcn_mfma_f32_16x16x32_f16(a1, qf[kf], c1, 0, 0, 0);
    }
#pragma unroll
    for (int kf = 6; kf < 12; ++kf) {
      const int col = (kf * 64 + g * 16) ^ amask7;
      half8 a0 = *(const half8*)(ksC + arow0 + col);
      half8 a1 = *(const half8*)(ksC + arow1 + col);
      e0 = __builtin_amdgcn_mfma_f32_16x16x32_f16(a0, qf[kf], e0, 0, 0, 0);
      e1 = __builtin_amdgcn_mfma_f32_16x16x32_f16(a1, qf[kf], e1, 0, 0, 0);
    }
    __builtin_amdgcn_s_setprio(0);
    c0 = c0 + e0;
    c1 = c1 + e1;

    // issue K(i+1) DMA into Ks[nxt]
    __builtin_amdgcn_sched_barrier(0);
    {
      const char* src = zbB + (size_t)s0n * 1536;
      char* dst = KsB + nxt * 49152;
#pragma unroll
      for (int k = 0; k < 6; ++k) GLD16(src + kgsw[k], dst + klds[k]);
    }

    if (kh == 1) {
#pragma unroll
      for (int r = 0; r < 4; ++r) {
        Cp[g * 4 + r][qt * 16 + li] = c0[r];
        Cp[16 + g * 4 + r][qt * 16 + li] = c1[r];
      }
    }
    asm volatile("s_waitcnt lgkmcnt(0)" ::: "memory");
    __builtin_amdgcn_s_barrier();  // bar B

    // ================= seg2 =================
    if (kh == 0) {
      const int* mk = Msk[i & 1];
      float p[8];
      float vmax = -3.0e38f;
#pragma unroll
      for (int r = 0; r < 4; ++r) {
        float sv0 = c0[r] + Cp[g * 4 + r][qt * 16 + li];
        float sv1 = c1[r] + Cp[16 + g * 4 + r][qt * 16 + li];
        if (!mk[g * 4 + r]) sv0 = NEG_INF;
        if (!mk[16 + g * 4 + r]) sv1 = NEG_INF;
        p[r] = sv0;
        p[4 + r] = sv1;
        vmax = fmaxf(vmax, fmaxf(sv0, sv1));
      }
      vmax = fmaxf(vmax, __shfl_xor(vmax, 16));
      vmax = fmaxf(vmax, __shfl_xor(vmax, 32));
      float Mn = fmaxf(mreg, vmax);
      float fec = __expf(mreg - Mn);
      mreg = Mn;
      float ts = 0.f;
#pragma unroll
      for (int r = 0; r < 8; ++r) {
        p[r] = __expf(p[r] - Mn);
        ts += p[r];
      }
      ts += __shfl_xor(ts, 16);
      ts += __shfl_xor(ts, 32);
      lreg = lreg * fec + ts;
      if (lane < 16) Fac[qt * 16 + li] = fec;
      *(half4v*)(PtB + pwoff0) =
          (half4v){(f16)p[0], (f16)p[1], (f16)p[2], (f16)p[3]};
      *(half4v*)(PtB + pwoff1) =
          (half4v){(f16)p[4], (f16)p[5], (f16)p[6], (f16)p[7]};
    }
    if (t < 32) Msk[(i + 1) & 1][t] = mnext;
    // V(i)+mask drained; the 6 younger K(i+1) DMAs stay in flight
    asm volatile("s_waitcnt vmcnt(6) lgkmcnt(0)" ::: "memory");
    __builtin_amdgcn_s_barrier();  // bar C

    // ================= seg3 =================
    {
      float fr[4][4];
#pragma unroll
      for (int qs = 0; qs < 4; ++qs)
#pragma unroll
        for (int r = 0; r < 4; ++r) fr[qs][r] = Fac[qs * 16 + g * 4 + r];
#pragma unroll
      for (int qs = 0; qs < 4; ++qs)
#pragma unroll
        for (int dt = 0; dt < 6; ++dt)
#pragma unroll
          for (int r = 0; r < 4; ++r) oacc[qs][dt][r] *= fr[qs][r];
      half8 pa[4];
#pragma unroll
      for (int qs = 0; qs < 4; ++qs) pa[qs] = *(const half8*)(PtB + ptoff[qs]);
      __builtin_amdgcn_s_setprio(1);
#pragma unroll
      for (int dt = 0; dt < 6; ++dt) {
        half8 vb = *(const half8*)(VsB + vroff + dt * 1024);
#pragma unroll
        for (int qs = 0; qs < 4; ++qs)
          oacc[qs][dt] =
              __builtin_amdgcn_mfma_f32_16x16x32_f16(pa[qs], vb, oacc[qs][dt], 0, 0, 0);
      }
      __builtin_amdgcn_s_setprio(0);
    }
    asm volatile("s_waitcnt vmcnt(0)" ::: "memory");  // K(i+1) landed
    __builtin_amdgcn_s_barrier();  // bar D
  }

  if (kh == 0 && lane < 16) Lfin[qt * 16 + li] = lreg;
  __syncthreads();

  // ---- epilogue: O/l, head max-pool over r (4 heads per label), store ----
#pragma unroll
  for (int qs = 0; qs < 4; ++qs) {
    float rl[4];
#pragma unroll
    for (int r = 0; r < 4; ++r) rl[r] = 1.0f / Lfin[qs * 16 + g * 4 + r];
    int e_loc = qs * 4 + g;
    float* od = out_m + ((size_t)b * E_ + (q0 >> 2) + e_loc) * D_ + dh * 96 + li;
#pragma unroll
    for (int dt = 0; dt < 6; ++dt) {
      float mv = oacc[qs][dt][0] * rl[0];
      mv = fmaxf(mv, oacc[qs][dt][1] * rl[1]);
      mv = fmaxf(mv, oacc[qs][dt][2] * rl[2]);
      mv = fmaxf(mv, oacc[qs][dt][3] * rl[3]);
      od[dt * 16] = mv;
    }
  }
}

// ---------------------------------------------------------------------------
// logits[b,e] = sum_d cls_w[e,d]*m[b,e,d] + cls_b[e]; one wave per (b,e)
// ---------------------------------------------------------------------------
__global__ __launch_bounds__(256) void k_logits(const float* __restrict__ cw,
                                                const float* __restrict__ cb,
                                                const float* __restrict__ m,
                                                float* __restrict__ out) {
  int t = threadIdx.x, w = t >> 6, lane = t & 63;
  int rid = blockIdx.x * 4 + w;  // 0..7999
  int b = rid / E_, e = rid - b * E_;
  const float* mr = m + (size_t)rid * D_;
  const float* cr = cw + (size_t)e * D_;
  float acc = 0.f;
#pragma unroll
  for (int i = 0; i < 12; ++i) acc += cr[i * 64 + lane] * mr[i * 64 + lane];
#pragma unroll
  for (int off = 32; off >= 1; off >>= 1) acc += __shfl_xor(acc, off);
  if (lane == 0) out[rid] = acc + cb[e];
}

// ---------------------------------------------------------------------------
extern "C" void kernel_launch(void* const* d_in, const int* in_sizes, int n_in,
                              void* d_out, int out_size, void* d_ws, size_t ws_size,
                              hipStream_t stream) {
  const float* h = (const float*)d_in[0];
  const int* amask = (const int*)d_in[1];
  const float* lf = (const float*)d_in[2];
  const float* Ww = (const float*)d_in[3];
  const float* Wb = (const float*)d_in[4];
  const float* cw = (const float*)d_in[5];
  const float* cb = (const float*)d_in[6];
  float* out = (float*)d_out;

  f16* zb = (f16*)d_ws;                     // 12288*768*2 = 18874368 B
  f16* ht = (f16*)((char*)d_ws + 18874368); // 4*768*3072*2 = 18874368 B

  k_transpose<<<dim3(48, 12, 4), 256, 0, stream>>>(h, ht);
  k_zgemm<<<dim3(192, 12), 256, 0, stream>>>(h, Ww, Wb, zb);
  k_attn<<<512, 512, 0, stream>>>(lf, zb, ht, amask, out + 8000);
  k_logits<<<2000, 256, 0, stream>>>(cw, cb, out + 8000, out);
}